// Round 2
// baseline (849.347 us; speedup 1.0000x reference)
//
#include <hip/hip_runtime.h>

#define SLEN 1024
#define NBATCH 32
#define NHEADS 4
#define HDIM 32
#define EMB 128
#define LSTRIDE 1040  // bf16 elements per LDS logit row (1024 + pad, 16B-aligned rows)

typedef short short8 __attribute__((ext_vector_type(8)));
typedef short short4v __attribute__((ext_vector_type(4)));
typedef float floatx4 __attribute__((ext_vector_type(4)));

__device__ __forceinline__ unsigned short f2bf(float f) {
    unsigned u = __float_as_uint(f);
    u += 0x7fffu + ((u >> 16) & 1u);   // round-to-nearest-even
    return (unsigned short)(u >> 16);
}
__device__ __forceinline__ float bf2f(unsigned short h) {
    return __uint_as_float(((unsigned)h) << 16);
}

// ---------------------------------------------------------------------------
// Kernel 1: q/k/v head projections (fp32 -> bf16 via MFMA), Wo -> bf16.
//   qb, kb : [N,H,S,32] bf16
//   vt     : [N,H,32,S] bf16 (transposed so PV B-frags are 16B contiguous)
//   Wq folded with 1/sqrt(128).
// NOTE: MFMA 16x16x32 output tile is N=16 wide; weights are 32x32, so each
// (tensor, head) needs TWO MFMAs (d=0..15 and d=16..31). Round-1 bug was
// issuing only one -> half the head dims were ws-poison.
// ---------------------------------------------------------------------------
__global__ __launch_bounds__(256) void proj_kernel(
    const float* __restrict__ vals, const float* __restrict__ keys,
    const float* __restrict__ qrys,
    const float* __restrict__ Wv, const float* __restrict__ Wk,
    const float* __restrict__ Wq, const float* __restrict__ Wo,
    unsigned short* __restrict__ qb, unsigned short* __restrict__ kb,
    unsigned short* __restrict__ vt, unsigned short* __restrict__ wo_bf)
{
    int b = blockIdx.x;
    int tid = threadIdx.x;
    if (b == 512) {  // Wo fp32 -> bf16 (128x128)
        #pragma unroll
        for (int i = 0; i < 64; ++i) {
            int idx = tid + (i << 8);
            wo_bf[idx] = f2bf(Wo[idx]);
        }
        return;
    }
    int n = b >> 4;
    int s0 = (b & 15) << 6;           // 64 rows per block
    int wave = tid >> 6, lane = tid & 63;
    int quad = lane >> 4, l16 = lane & 15;
    int srow = s0 + (wave << 4);      // this wave's 16 rows

    // B-fragments: B[k=j][n=d] = W[d][j]; half 0: d=l16, half 1: d=16+l16
    short8 bw[3][2];
    const float* Ws[3] = { Wv, Wk, Wq };
    const float scal[3] = { 1.0f, 1.0f, 0.08838834764831845f }; // 1/sqrt(128) folded into Wq
    #pragma unroll
    for (int t = 0; t < 3; ++t) {
        float s = scal[t];
        #pragma unroll
        for (int hh = 0; hh < 2; ++hh) {
            const float* wp = Ws[t] + (hh * 16 + l16) * 32 + quad * 8;
            float4 w0 = *(const float4*)wp;
            float4 w1 = *(const float4*)(wp + 4);
            short8 r;
            r[0] = (short)f2bf(w0.x * s); r[1] = (short)f2bf(w0.y * s);
            r[2] = (short)f2bf(w0.z * s); r[3] = (short)f2bf(w0.w * s);
            r[4] = (short)f2bf(w1.x * s); r[5] = (short)f2bf(w1.y * s);
            r[6] = (short)f2bf(w1.z * s); r[7] = (short)f2bf(w1.w * s);
            bw[t][hh] = r;
        }
    }

    const float* srcs[3] = { vals, keys, qrys };
    #pragma unroll
    for (int t = 0; t < 3; ++t) {
        const float* src = srcs[t];
        #pragma unroll
        for (int h = 0; h < NHEADS; ++h) {
            size_t nh = (size_t)(n * NHEADS + h);
            // A-frag: x[rows srow..srow+15][k=embedding 32 of head h]
            const float* xp = src + ((size_t)(n * SLEN + srow + l16) * EMB + h * HDIM + quad * 8);
            float4 x0 = *(const float4*)xp;
            float4 x1 = *(const float4*)(xp + 4);
            short8 a;
            a[0] = (short)f2bf(x0.x); a[1] = (short)f2bf(x0.y);
            a[2] = (short)f2bf(x0.z); a[3] = (short)f2bf(x0.w);
            a[4] = (short)f2bf(x1.x); a[5] = (short)f2bf(x1.y);
            a[6] = (short)f2bf(x1.z); a[7] = (short)f2bf(x1.w);
            floatx4 c0 = {0.f, 0.f, 0.f, 0.f};
            floatx4 c1 = {0.f, 0.f, 0.f, 0.f};
            c0 = __builtin_amdgcn_mfma_f32_16x16x32_bf16(a, bw[t][0], c0, 0, 0, 0);
            c1 = __builtin_amdgcn_mfma_f32_16x16x32_bf16(a, bw[t][1], c1, 0, 0, 0);
            // C: local row = quad*4+r (s), col = l16 (c0: d=l16, c1: d=16+l16)
            if (t == 0) {
                // vt[n][h][d][s], 4 consecutive s per lane -> 8B packed store
                short4v p0, p1;
                p0[0] = (short)f2bf(c0[0]); p0[1] = (short)f2bf(c0[1]);
                p0[2] = (short)f2bf(c0[2]); p0[3] = (short)f2bf(c0[3]);
                p1[0] = (short)f2bf(c1[0]); p1[1] = (short)f2bf(c1[1]);
                p1[2] = (short)f2bf(c1[2]); p1[3] = (short)f2bf(c1[3]);
                *(short4v*)(vt + (nh * HDIM + l16) * SLEN + srow + quad * 4) = p0;
                *(short4v*)(vt + (nh * HDIM + 16 + l16) * SLEN + srow + quad * 4) = p1;
            } else {
                unsigned short* dst = (t == 1 ? kb : qb) +
                    (nh * SLEN + srow + quad * 4) * HDIM;
                #pragma unroll
                for (int r = 0; r < 4; ++r) {
                    dst[r * HDIM + l16]      = f2bf(c0[r]);
                    dst[r * HDIM + 16 + l16] = f2bf(c1[r]);
                }
            }
        }
    }
}

// ---------------------------------------------------------------------------
// Kernel 2: per (n, 16-row block), loop over the 4 heads:
//   QK^T (MFMA) -> bf16 logits in LDS -> masked softmax (shuffle reduce)
//   -> write normalized weights (f32) to d_out -> PV with unnormalized e
//   (1/sum applied per output row in epilogue) -> attnV bf16 to ws.
// ---------------------------------------------------------------------------
__global__ __launch_bounds__(256, 3) void attn_kernel(
    const unsigned short* __restrict__ qb, const unsigned short* __restrict__ kb,
    const unsigned short* __restrict__ vt, const int* __restrict__ mask,
    float* __restrict__ wout, unsigned short* __restrict__ attnv)
{
    __shared__ unsigned short eb[16 * LSTRIDE];   // logits, then e (bf16)
    __shared__ float partial[4][16][32];          // per-wave PV partials
    __shared__ float rowinv[16];

    int bid = blockIdx.x;
    int n = bid >> 6;            // 64 row-blocks per batch
    int r0 = (bid & 63) << 4;    // 16 query rows per block
    int tid = threadIdx.x;
    int wave = tid >> 6, lane = tid & 63;
    int quad = lane >> 4, l16 = lane & 15;
    int srow = tid >> 4, c16 = tid & 15;   // softmax mapping: 16 threads per row

    // ---- mask bits: read mask once for this row block, keep as 64-bit reg ----
    // bit (i*8+j) <-> col (c16+16*i)*8 + j
    unsigned long long mbits = 0ull;
    const int* mrow = mask + (size_t)(n * SLEN + r0 + srow) * SLEN;
    #pragma unroll
    for (int i = 0; i < 8; ++i) {
        int cb = (c16 + (i << 4)) << 3;
        int4 a = *(const int4*)(mrow + cb);
        int4 bq = *(const int4*)(mrow + cb + 4);
        unsigned bits = 0;
        bits |= (unsigned)(a.x != 0);
        bits |= (unsigned)(a.y != 0) << 1;
        bits |= (unsigned)(a.z != 0) << 2;
        bits |= (unsigned)(a.w != 0) << 3;
        bits |= (unsigned)(bq.x != 0) << 4;
        bits |= (unsigned)(bq.y != 0) << 5;
        bits |= (unsigned)(bq.z != 0) << 6;
        bits |= (unsigned)(bq.w != 0) << 7;
        mbits |= (unsigned long long)bits << (i * 8);
    }

    for (int h = 0; h < NHEADS; ++h) {
        size_t nh = (size_t)(n * NHEADS + h);

        // ---- QK^T into LDS (bf16, already scaled by 1/sqrt(128) via Wq) ----
        short8 afrag = *(const short8*)(qb + (nh * SLEN + r0 + l16) * HDIM + quad * 8);
        const unsigned short* kbase = kb + nh * SLEN * HDIM;
        #pragma unroll
        for (int t = 0; t < 16; ++t) {
            int ct = (wave << 4) + t;                 // col tile (16 cols)
            short8 bfrag = *(const short8*)(kbase + (size_t)((ct << 4) + l16) * HDIM + quad * 8);
            floatx4 c = {0.f, 0.f, 0.f, 0.f};
            c = __builtin_amdgcn_mfma_f32_16x16x32_bf16(afrag, bfrag, c, 0, 0, 0);
            int colb = (ct << 4) + l16;
            #pragma unroll
            for (int r = 0; r < 4; ++r)
                eb[(quad * 4 + r) * LSTRIDE + colb] = f2bf(c[r]);
        }
        __syncthreads();

        // ---- softmax over row srow (64 cols per thread, 16 threads/row) ----
        unsigned short* erow = eb + srow * LSTRIDE;
        float mx = -3.0e38f;
        #pragma unroll
        for (int i = 0; i < 8; ++i) {
            int cb = (c16 + (i << 4)) << 3;
            short8 v = *(const short8*)(erow + cb);
            unsigned bits = (unsigned)(mbits >> (i * 8)) & 0xffu;
            #pragma unroll
            for (int j = 0; j < 8; ++j) {
                float x = ((bits >> j) & 1u) ? bf2f((unsigned short)v[j]) : -1e20f;
                mx = fmaxf(mx, x);
            }
        }
        #pragma unroll
        for (int off = 8; off > 0; off >>= 1)
            mx = fmaxf(mx, __shfl_xor(mx, off, 16));

        float sum = 0.f;
        #pragma unroll
        for (int i = 0; i < 8; ++i) {
            int cb = (c16 + (i << 4)) << 3;
            short8 v = *(const short8*)(erow + cb);
            unsigned bits = (unsigned)(mbits >> (i * 8)) & 0xffu;
            short8 e8;
            #pragma unroll
            for (int j = 0; j < 8; ++j) {
                float e = 0.f;
                if ((bits >> j) & 1u) e = __expf(bf2f((unsigned short)v[j]) - mx);
                sum += e;
                e8[j] = (short)f2bf(e);
            }
            *(short8*)(erow + cb) = e8;   // unnormalized e, bf16
        }
        #pragma unroll
        for (int off = 8; off > 0; off >>= 1)
            sum += __shfl_xor(sum, off, 16);
        float inv = 1.0f / sum;
        if (c16 == 0) rowinv[srow] = inv;

        // ---- write normalized attention weights (f32) ----
        float* wrow = wout + (nh * SLEN + r0 + srow) * SLEN;
        #pragma unroll
        for (int i = 0; i < 8; ++i) {
            int cb = (c16 + (i << 4)) << 3;
            short8 e8 = *(const short8*)(erow + cb);
            float4 w0, w1;
            w0.x = bf2f((unsigned short)e8[0]) * inv;
            w0.y = bf2f((unsigned short)e8[1]) * inv;
            w0.z = bf2f((unsigned short)e8[2]) * inv;
            w0.w = bf2f((unsigned short)e8[3]) * inv;
            w1.x = bf2f((unsigned short)e8[4]) * inv;
            w1.y = bf2f((unsigned short)e8[5]) * inv;
            w1.z = bf2f((unsigned short)e8[6]) * inv;
            w1.w = bf2f((unsigned short)e8[7]) * inv;
            *(float4*)(wrow + cb) = w0;
            *(float4*)(wrow + cb + 4) = w1;
        }
        __syncthreads();   // all e visible before PV

        // ---- PV: out[m][d] = inv[m] * sum_l e[m][l] * V[l][d] ----
        floatx4 acc0 = {0.f, 0.f, 0.f, 0.f}, acc1 = {0.f, 0.f, 0.f, 0.f};
        const unsigned short* vbase = vt + nh * HDIM * SLEN;
        #pragma unroll
        for (int i = 0; i < 8; ++i) {
            int kt = (wave << 3) + i;   // 32-wide l tile
            short8 a8 = *(const short8*)(eb + l16 * LSTRIDE + (kt << 5) + quad * 8);
            short8 b0 = *(const short8*)(vbase + (size_t)l16 * SLEN + (kt << 5) + quad * 8);
            short8 b1 = *(const short8*)(vbase + (size_t)(16 + l16) * SLEN + (kt << 5) + quad * 8);
            acc0 = __builtin_amdgcn_mfma_f32_16x16x32_bf16(a8, b0, acc0, 0, 0, 0);
            acc1 = __builtin_amdgcn_mfma_f32_16x16x32_bf16(a8, b1, acc1, 0, 0, 0);
        }
        #pragma unroll
        for (int r = 0; r < 4; ++r) {
            partial[wave][quad * 4 + r][l16] = acc0[r];
            partial[wave][quad * 4 + r][16 + l16] = acc1[r];
        }
        __syncthreads();

        // ---- cross-wave reduce + write attnV (bf16) ----
        {
            int m = tid >> 4;
            int d0 = (tid & 15) << 1;
            float s0 = partial[0][m][d0] + partial[1][m][d0] +
                       partial[2][m][d0] + partial[3][m][d0];
            float s1 = partial[0][m][d0 + 1] + partial[1][m][d0 + 1] +
                       partial[2][m][d0 + 1] + partial[3][m][d0 + 1];
            float iv = rowinv[m];
            unsigned pk = (unsigned)f2bf(s0 * iv) | ((unsigned)f2bf(s1 * iv) << 16);
            *(unsigned*)(attnv + (size_t)(n * SLEN + r0 + m) * EMB + h * HDIM + d0) = pk;
        }
        __syncthreads();   // protect eb/partial before next head
    }
}

// ---------------------------------------------------------------------------
// Kernel 3: out = attnV @ Wo^T + bo   (M=32768, N=128, K=128, bf16 MFMA)
// ---------------------------------------------------------------------------
__global__ __launch_bounds__(256) void out_kernel(
    const unsigned short* __restrict__ attnv, const unsigned short* __restrict__ wo_bf,
    const float* __restrict__ bo, float* __restrict__ out)
{
    int tid = threadIdx.x;
    int wave = tid >> 6, lane = tid & 63;
    int quad = lane >> 4, l16 = lane & 15;
    int m0 = blockIdx.x * 64 + (wave << 4);

    short8 afr[4];
    const unsigned short* ap = attnv + (size_t)(m0 + l16) * EMB + quad * 8;
    #pragma unroll
    for (int ks = 0; ks < 4; ++ks) afr[ks] = *(const short8*)(ap + ks * 32);

    #pragma unroll
    for (int ct = 0; ct < 8; ++ct) {
        floatx4 c = {0.f, 0.f, 0.f, 0.f};
        const unsigned short* bp = wo_bf + ((ct << 4) + l16) * EMB + quad * 8;
        #pragma unroll
        for (int ks = 0; ks < 4; ++ks) {
            short8 b = *(const short8*)(bp + ks * 32);
            c = __builtin_amdgcn_mfma_f32_16x16x32_bf16(afr[ks], b, c, 0, 0, 0);
        }
        int col = (ct << 4) + l16;
        float bias = bo[col];
        #pragma unroll
        for (int r = 0; r < 4; ++r)
            out[(size_t)(m0 + quad * 4 + r) * EMB + col] = c[r] + bias;
    }
}

// ---------------------------------------------------------------------------
extern "C" void kernel_launch(void* const* d_in, const int* in_sizes, int n_in,
                              void* d_out, int out_size, void* d_ws, size_t ws_size,
                              hipStream_t stream)
{
    (void)in_sizes; (void)n_in; (void)out_size; (void)ws_size;
    const float* vals = (const float*)d_in[0];
    const float* keys = (const float*)d_in[1];
    const float* qrys = (const float*)d_in[2];
    const int*   mask = (const int*)d_in[3];
    const float* Wv   = (const float*)d_in[4];
    const float* Wk   = (const float*)d_in[5];
    const float* Wq   = (const float*)d_in[6];
    const float* Wo   = (const float*)d_in[7];
    const float* bo   = (const float*)d_in[8];
    float* out = (float*)d_out;

    const size_t NHS = (size_t)NBATCH * NHEADS * SLEN * HDIM;  // 4,194,304
    unsigned short* ws = (unsigned short*)d_ws;
    unsigned short* qb    = ws;
    unsigned short* kbuf  = qb + NHS;
    unsigned short* vt    = kbuf + NHS;
    unsigned short* av    = vt + NHS;                          // [N,S,128] bf16
    unsigned short* wo_bf = av + (size_t)NBATCH * SLEN * EMB;  // [128,128] bf16
    float* wout = out + (size_t)NBATCH * SLEN * EMB;           // weights region of d_out

    hipLaunchKernelGGL(proj_kernel, dim3(513), dim3(256), 0, stream,
                       vals, keys, qrys, Wv, Wk, Wq, Wo, qb, kbuf, vt, wo_bf);
    hipLaunchKernelGGL(attn_kernel, dim3(NBATCH * 64), dim3(256), 0, stream,
                       qb, kbuf, vt, mask, wout, av);
    hipLaunchKernelGGL(out_kernel, dim3((NBATCH * SLEN) / 64), dim3(256), 0, stream,
                       av, wo_bf, bo, out);
}